// Round 16
// baseline (255.291 us; speedup 1.0000x reference)
//
#include <hip/hip_runtime.h>
#include <hip/hip_bf16.h>

typedef __bf16 bf16x8 __attribute__((ext_vector_type(8)));
typedef float  f32x4  __attribute__((ext_vector_type(4)));

#define GRID2 256
// d_out offsets (floats)
#define O_FINAL 0
#define O_H     512
#define O_C     1049088      // 512 + 4*256*1024
#define O_NORM  2097664      // O_C + 4*256*1024

__device__ __forceinline__ void gridbar(int* slot) {
  __syncthreads();
  if (threadIdx.x == 0) {
    __hip_atomic_fetch_add(slot, 1, __ATOMIC_ACQ_REL, __HIP_MEMORY_SCOPE_AGENT);
    while (__hip_atomic_load(slot, __ATOMIC_RELAXED, __HIP_MEMORY_SCOPE_AGENT) < GRID2)
      __builtin_amdgcn_s_sleep(2);
    (void)__hip_atomic_load(slot, __ATOMIC_ACQUIRE, __HIP_MEMORY_SCOPE_AGENT);
  }
  __syncthreads();
}

__device__ __forceinline__ bf16x8 cvt8(float4 a, float4 b) {
  bf16x8 r;
  r[0] = (__bf16)a.x; r[1] = (__bf16)a.y; r[2] = (__bf16)a.z; r[3] = (__bf16)a.w;
  r[4] = (__bf16)b.x; r[5] = (__bf16)b.y; r[6] = (__bf16)b.z; r[7] = (__bf16)b.w;
  return r;
}

// ============ ff staged core (R9-proven): 64 A-rows x [16c x 4g], 8 waves ============
template<int K>
__device__ __forceinline__ void tile_gemm_ff(const float* __restrict__ A,
                                             const float* __restrict__ W,
                                             int r0, int j0, char* lds,
                                             f32x4 acc[2]) {
  constexpr int NK = K / 64;
  constexpr int D = 4;
  const int t = threadIdx.x, lane = t & 63, wave = t >> 6;
  const int rf = wave & 3, gg = wave >> 2;
  const int tr = t >> 3, chunk = t & 7;
  const float* wsrc = W + (size_t)((tr >> 4) * 1024 + j0 + (tr & 15)) * K + chunk * 8;
  const float* asrc = A + (size_t)(r0 + tr) * K + chunk * 8;
  const int sw_off = (chunk ^ (tr & 7)) << 4;
  const int woff = 8192 + tr * 128 + sw_off;
  const int aoff = tr * 128 + sw_off;
  const int a_tr  = rf * 16 + (lane & 15);
  const int w_tr0 = gg * 32 + (lane & 15);
  const int w_tr1 = w_tr0 + 16;
  const int ksel  = lane >> 4;

  float4 wp[D][2], ap[D][2];
#pragma unroll
  for (int d = 0; d < D; ++d) {
    wp[d][0] = *(const float4*)(wsrc + d * 64);
    wp[d][1] = *(const float4*)(wsrc + d * 64 + 4);
    ap[d][0] = *(const float4*)(asrc + d * 64);
    ap[d][1] = *(const float4*)(asrc + d * 64 + 4);
  }
#pragma unroll
  for (int s = 0; s < NK; ++s) {
    const int sl = s % D;
    char* buf = lds + (s & 1) * 16384;
    *(bf16x8*)(buf + aoff) = cvt8(ap[sl][0], ap[sl][1]);
    *(bf16x8*)(buf + woff) = cvt8(wp[sl][0], wp[sl][1]);
    if (s + D < NK) {
      wp[sl][0] = *(const float4*)(wsrc + (s + D) * 64);
      wp[sl][1] = *(const float4*)(wsrc + (s + D) * 64 + 4);
      ap[sl][0] = *(const float4*)(asrc + (s + D) * 64);
      ap[sl][1] = *(const float4*)(asrc + (s + D) * 64 + 4);
    }
    __syncthreads();
#pragma unroll
    for (int s2 = 0; s2 < 2; ++s2) {
      const int chk = s2 * 4 + ksel;
      bf16x8 af  = *(const bf16x8*)(buf + a_tr * 128 + ((chk ^ (a_tr & 7)) << 4));
      bf16x8 wf0 = *(const bf16x8*)(buf + 8192 + w_tr0 * 128 + ((chk ^ (w_tr0 & 7)) << 4));
      bf16x8 wf1 = *(const bf16x8*)(buf + 8192 + w_tr1 * 128 + ((chk ^ (w_tr1 & 7)) << 4));
      acc[0] = __builtin_amdgcn_mfma_f32_16x16x32_bf16(af, wf0, acc[0], 0, 0, 0);
      acc[1] = __builtin_amdgcn_mfma_f32_16x16x32_bf16(af, wf1, acc[1], 0, 0, 0);
    }
  }
}

// ============ k_scores: pure scores, 4096 blocks x 256 thr (R3-proven) ============
__global__ __launch_bounds__(256) void k_scores(const float* __restrict__ AO,
                                                const float* __restrict__ Wattn,
                                                float* __restrict__ sc) {
  const int lane = threadIdx.x & 63, wave = threadIdx.x >> 6;
  const float* wy = Wattn + 1024;
  float4 wv[4];
#pragma unroll
  for (int q = 0; q < 4; ++q) wv[q] = *(const float4*)(wy + lane * 4 + 256 * q);
  const int row0 = (blockIdx.x * 4 + wave) * 4;
  float a4[4];
#pragma unroll
  for (int rr = 0; rr < 4; ++rr) {
    const float4* rp = (const float4*)(AO + (size_t)(row0 + rr) * 1024);
    float a = 0.f;
#pragma unroll
    for (int q = 0; q < 4; ++q) {
      float4 v = rp[lane + 64 * q];
      a += v.x * wv[q].x + v.y * wv[q].y + v.z * wv[q].z + v.w * wv[q].w;
    }
    a4[rr] = a;
  }
#pragma unroll
  for (int rr = 0; rr < 4; ++rr) {
    float a = a4[rr];
#pragma unroll
    for (int off = 32; off; off >>= 1) a += __shfl_xor(a, off, 64);
    if (lane == 0) {
      int row = row0 + rr;                      // row = pos*256 + b
      sc[(row & 255) * 256 + (row >> 8)] = a;   // [b][pos]
    }
  }
}

// ============ k_mid: Gh (blocks 0..1023) | smx-512 (1024..1279) ============
__global__ __launch_bounds__(512) void k_mid(
    const float* __restrict__ sc,   const float* __restrict__ AO,
    const float* __restrict__ inp,  const float* __restrict__ Wemb,
    const float* __restrict__ bemb,
    const float* __restrict__ h0,
    const float* __restrict__ Whh0, const float* __restrict__ Whh_r,
    const float* __restrict__ bih0, const float* __restrict__ bhh0,
    const float* __restrict__ bih_r, const float* __restrict__ bhh_r,
    float* __restrict__ Gh,
    float* __restrict__ norm_out,   __bf16* __restrict__ xb) {
  __shared__ char smem[32768];
  const int t = threadIdx.x, lane = t & 63, wave = t >> 6;
  if (blockIdx.x < 1024) {
    const int j = blockIdx.x;
    const int l = j >> 8, inner = j & 255;
    const int cb = inner & 63, rb = inner >> 6;
    const int j0 = cb * 16, r0 = rb * 64;
    const float* A  = h0 + (size_t)l * 262144;
    const float* W  = (l == 0) ? Whh0 : (Whh_r + (size_t)(l - 1) * 4194304);
    const float* bi = (l == 0) ? bih0 : (bih_r + (size_t)(l - 1) * 4096);
    const float* bh = (l == 0) ? bhh0 : (bhh_r + (size_t)(l - 1) * 4096);
    f32x4 acc[2] = {};
    tile_gemm_ff<1024>(A, W, r0, j0, smem, acc);
    float* Go = Gh + (size_t)l * 1048576;
    const int rf = wave & 3, gg = wave >> 2;
    const int col = j0 + (lane & 15);
    const int rbase = r0 + rf * 16 + ((lane >> 4) << 2);
#pragma unroll
    for (int gi = 0; gi < 2; ++gi) {
      const int cg = (gg * 2 + gi) * 1024 + col;
#pragma unroll
      for (int q = 0; q < 4; ++q)
        Go[(size_t)(rbase + q) * 4096 + cg] = acc[gi][q] + bi[cg] + bh[cg];
    }
    return;
  }
  // smx at 512 thr
  float* red  = (float*)smem;
  float* nv_l = (float*)(smem + 64);
  const int b = blockIdx.x - 1024;
  float s = (t < 256) ? sc[b * 256 + t] : -3.4e38f;
  float m = s;
#pragma unroll
  for (int off = 32; off; off >>= 1) m = fmaxf(m, __shfl_xor(m, off, 64));
  if (lane == 0) red[wave] = m;
  __syncthreads();
  m = red[0];
#pragma unroll
  for (int w2 = 1; w2 < 8; ++w2) m = fmaxf(m, red[w2]);
  float e = (t < 256) ? __expf(s - m) : 0.f;
  float sum = e;
#pragma unroll
  for (int off = 32; off; off >>= 1) sum += __shfl_xor(sum, off, 64);
  __syncthreads();
  if (lane == 0) red[wave] = sum;
  __syncthreads();
  sum = red[0];
#pragma unroll
  for (int w2 = 1; w2 < 8; ++w2) sum += red[w2];
  float nv = e / sum;
  if (t < 256) {
    norm_out[b * 256 + t] = nv;
    if (t >= 224) nv_l[t - 224] = nv;
  }
  __syncthreads();
  float a0 = 0.f, a1 = 0.f;
  const float* base = AO + ((size_t)224 * 256 + b) * 1024;
#pragma unroll 4
  for (int i = 0; i < 32; ++i) {
    float w = nv_l[i];
    const float* rp = base + (size_t)i * 262144;
    a0 += w * rp[t];
    a1 += w * rp[t + 512];
  }
  xb[(size_t)b * 1536 + t]       = (__bf16)(8.0f * a0);
  xb[(size_t)b * 1536 + t + 512] = (__bf16)(8.0f * a1);
  float e2 = inp[b * 2] * Wemb[t * 2] + inp[b * 2 + 1] * Wemb[t * 2 + 1] + bemb[t];
  xb[(size_t)b * 1536 + 1024 + t] = (__bf16)fmaxf(e2, 0.f);
}

// ============ layer body (R14-proven 152.5µs config, verbatim) ============
template<int KA>
__device__ __forceinline__ void layer_body(const __bf16* __restrict__ A,
                                           const float* __restrict__ Wih,
                                           const float* __restrict__ Gh,
                                           const float* __restrict__ c0l,
                                           float* __restrict__ h_out,
                                           float* __restrict__ c_out,
                                           __bf16* __restrict__ hb,
                                           char* smem) {
  constexpr int NK = KA / 64;
  constexpr int D = 4;
  float* exch = (float*)(smem + 32768);
  const int t = threadIdx.x, lane = t & 63, wave = t >> 6;
  const int rf = wave & 3, gg = wave >> 2;
  const int cb = blockIdx.x & 63, rb = blockIdx.x >> 6;
  const int j0 = cb * 16, r0 = rb * 64;
  const int tr = t >> 3, chunk = t & 7;
  const float*  wsrc = Wih + (size_t)((tr >> 4) * 1024 + j0 + (tr & 15)) * KA + chunk * 8;
  const __bf16* asrc = A + (size_t)(r0 + tr) * KA + chunk * 8;
  const int sw_off = (chunk ^ (tr & 7)) << 4;
  const int woff = 8192 + tr * 128 + sw_off;
  const int aoff = tr * 128 + sw_off;
  const int a_tr  = rf * 16 + (lane & 15);
  const int w_tr0 = gg * 32 + (lane & 15);
  const int w_tr1 = w_tr0 + 16;
  const int ksel  = lane >> 4;
  f32x4 acc[2] = {};
  float4 wp[D][2]; bf16x8 ap[D];
#pragma unroll
  for (int d = 0; d < D; ++d) {
    wp[d][0] = *(const float4*)(wsrc + d * 64);
    wp[d][1] = *(const float4*)(wsrc + d * 64 + 4);
    ap[d]    = *(const bf16x8*)(asrc + d * 64);
  }
#pragma unroll
  for (int s = 0; s < NK; ++s) {
    const int sl = s % D;
    char* buf = smem + (s & 1) * 16384;
    *(bf16x8*)(buf + aoff) = ap[sl];
    *(bf16x8*)(buf + woff) = cvt8(wp[sl][0], wp[sl][1]);
    if (s + D < NK) {
      wp[sl][0] = *(const float4*)(wsrc + (s + D) * 64);
      wp[sl][1] = *(const float4*)(wsrc + (s + D) * 64 + 4);
      ap[sl]    = *(const bf16x8*)(asrc + (s + D) * 64);
    }
    __syncthreads();
#pragma unroll
    for (int s2 = 0; s2 < 2; ++s2) {
      const int chk = s2 * 4 + ksel;
      bf16x8 af  = *(const bf16x8*)(buf + a_tr * 128 + ((chk ^ (a_tr & 7)) << 4));
      bf16x8 wf0 = *(const bf16x8*)(buf + 8192 + w_tr0 * 128 + ((chk ^ (w_tr0 & 7)) << 4));
      bf16x8 wf1 = *(const bf16x8*)(buf + 8192 + w_tr1 * 128 + ((chk ^ (w_tr1 & 7)) << 4));
      acc[0] = __builtin_amdgcn_mfma_f32_16x16x32_bf16(af, wf0, acc[0], 0, 0, 0);
      acc[1] = __builtin_amdgcn_mfma_f32_16x16x32_bf16(af, wf1, acc[1], 0, 0, 0);
    }
  }
  const int col = j0 + (lane & 15);
  const int rbase = r0 + rf * 16 + ((lane >> 4) << 2);
  const int eidx = ((lane >> 4) << 2) * 16 + (lane & 15);
#pragma unroll
  for (int gi = 0; gi < 2; ++gi) {
    const float* gp = Gh + (size_t)rbase * 4096 + (gg * 2 + gi) * 1024 + col;
#pragma unroll
    for (int q = 0; q < 4; ++q) acc[gi][q] += gp[(size_t)q * 4096];
  }
  __syncthreads();
  if (gg == 1) {
#pragma unroll
    for (int gi = 0; gi < 2; ++gi)
#pragma unroll
      for (int q = 0; q < 4; ++q)
        exch[(rf * 2 + gi) * 256 + eidx + q * 16] = acc[gi][q];
  }
  __syncthreads();
  if (gg == 0) {
#pragma unroll
    for (int q = 0; q < 4; ++q) {
      const int row = rbase + q;
      float gv = exch[(rf * 2 + 0) * 256 + eidx + q * 16];
      float ov = exch[(rf * 2 + 1) * 256 + eidx + q * 16];
      float si = 1.f / (1.f + __expf(-acc[0][q]));
      float sf = 1.f / (1.f + __expf(-acc[1][q]));
      float so = 1.f / (1.f + __expf(-ov));
      float c2 = sf * c0l[(size_t)row * 1024 + col] + si * tanhf(gv);
      float h2 = so * tanhf(c2);
      h_out[(size_t)row * 1024 + col] = h2;
      c_out[(size_t)row * 1024 + col] = c2;
      hb[(size_t)row * 1024 + col] = (__bf16)h2;
    }
  }
}

// ============ k_tail: persistent smx -> 4 layers -> final (grid 256) ============
__global__ __launch_bounds__(512) void k_tail(
    const float* __restrict__ sc,   const float* __restrict__ AO,
    const float* __restrict__ inp,  const float* __restrict__ Wemb,
    const float* __restrict__ bemb,
    const float* __restrict__ Wih0, const float* __restrict__ Wih_r,
    const float* __restrict__ Gh,   const float* __restrict__ c0,
    const float* __restrict__ Wout, const float* __restrict__ bout,
    float* __restrict__ out, int* __restrict__ bar,
    __bf16* __restrict__ xb, __bf16* __restrict__ hb) {
  __shared__ char smem[40960];
  const int t = threadIdx.x, lane = t & 63, wave = t >> 6;

  // ---- phase 1: smx (one block per b, 512 thr) ----
  {
    float* red  = (float*)smem;
    float* nv_l = (float*)(smem + 64);
    const int b = blockIdx.x;
    float s = (t < 256) ? sc[b * 256 + t] : -3.4e38f;
    float m = s;
#pragma unroll
    for (int off = 32; off; off >>= 1) m = fmaxf(m, __shfl_xor(m, off, 64));
    if (lane == 0) red[wave] = m;
    __syncthreads();
    m = red[0];
#pragma unroll
    for (int w2 = 1; w2 < 8; ++w2) m = fmaxf(m, red[w2]);
    float e = (t < 256) ? __expf(s - m) : 0.f;
    float sum = e;
#pragma unroll
    for (int off = 32; off; off >>= 1) sum += __shfl_xor(sum, off, 64);
    __syncthreads();
    if (lane == 0) red[wave] = sum;
    __syncthreads();
    sum = red[0];
#pragma unroll
    for (int w2 = 1; w2 < 8; ++w2) sum += red[w2];
    float nv = e / sum;
    if (t < 256) {
      out[O_NORM + b * 256 + t] = nv;
      if (t >= 224) nv_l[t - 224] = nv;
    }
    __syncthreads();
    float a0 = 0.f, a1 = 0.f;
    const float* base = AO + ((size_t)224 * 256 + b) * 1024;
#pragma unroll 4
    for (int i = 0; i < 32; ++i) {
      float w = nv_l[i];
      const float* rp = base + (size_t)i * 262144;
      a0 += w * rp[t];
      a1 += w * rp[t + 512];
    }
    xb[(size_t)b * 1536 + t]       = (__bf16)(8.0f * a0);
    xb[(size_t)b * 1536 + t + 512] = (__bf16)(8.0f * a1);
    float e2 = inp[b * 2] * Wemb[t * 2] + inp[b * 2 + 1] * Wemb[t * 2 + 1] + bemb[t];
    xb[(size_t)b * 1536 + 1024 + t] = (__bf16)fmaxf(e2, 0.f);
  }
  gridbar(bar + 0 * 32);

  // ---- layers ----
  layer_body<1536>(xb, Wih0, Gh, c0, out + O_H, out + O_C, hb, smem);
  gridbar(bar + 1 * 32);
#pragma unroll 1
  for (int l = 1; l < 4; ++l) {
    layer_body<1024>(hb + (size_t)(l - 1) * 262144,
                     Wih_r + (size_t)(l - 1) * 4194304,
                     Gh + (size_t)l * 1048576,
                     c0 + (size_t)l * 262144,
                     out + O_H + (size_t)l * 262144,
                     out + O_C + (size_t)l * 262144,
                     hb + (size_t)l * 262144, smem);
    gridbar(bar + (l + 1) * 32);
  }

  // ---- final: out[b,:2] = h3[b,:] @ Wout^T + bout (blocks 0..31, 8 b each) ----
  if (blockIdx.x < 32) {
    const float* h3 = out + O_H + 3 * 262144;
    const int bb = blockIdx.x * 8 + wave;
    const float4* hp = (const float4*)(h3 + (size_t)bb * 1024);
    const float4* w0 = (const float4*)Wout;
    const float4* w1 = (const float4*)(Wout + 1024);
    float a0 = 0.f, a1 = 0.f;
#pragma unroll
    for (int q = 0; q < 4; ++q) {
      float4 hv = hp[lane + 64 * q];
      float4 v0 = w0[lane + 64 * q];
      float4 v1 = w1[lane + 64 * q];
      a0 += hv.x * v0.x + hv.y * v0.y + hv.z * v0.z + hv.w * v0.w;
      a1 += hv.x * v1.x + hv.y * v1.y + hv.z * v1.z + hv.w * v1.w;
    }
#pragma unroll
    for (int off = 32; off; off >>= 1) {
      a0 += __shfl_xor(a0, off, 64);
      a1 += __shfl_xor(a1, off, 64);
    }
    if (lane == 0) {
      out[bb * 2]     = a0 + bout[0];
      out[bb * 2 + 1] = a1 + bout[1];
    }
  }
}

extern "C" void kernel_launch(void* const* d_in, const int* in_sizes, int n_in,
                              void* d_out, int out_size, void* d_ws, size_t ws_size,
                              hipStream_t stream) {
  const float* inp    = (const float*)d_in[0];
  const float* h0     = (const float*)d_in[1];
  const float* c0     = (const float*)d_in[2];
  const float* AO     = (const float*)d_in[3];
  const float* Wemb   = (const float*)d_in[4];
  const float* bemb   = (const float*)d_in[5];
  const float* Wattn  = (const float*)d_in[6];
  // d_in[7] = b_attn (cancels in softmax)
  const float* Wih0   = (const float*)d_in[8];
  const float* Whh0   = (const float*)d_in[9];
  const float* bih0   = (const float*)d_in[10];
  const float* bhh0   = (const float*)d_in[11];
  const float* Wih_r  = (const float*)d_in[12];
  const float* Whh_r  = (const float*)d_in[13];
  const float* bih_r  = (const float*)d_in[14];
  const float* bhh_r  = (const float*)d_in[15];
  const float* Wout   = (const float*)d_in[16];
  const float* bout   = (const float*)d_in[17];

  float* out = (float*)d_out;
  char* ws = (char*)d_ws;

  int*    bar = (int*)ws;                     // 4 KB barrier slots
  float*  sc  = (float*)(ws + 4096);          // 256 KB [256][256]
  float*  Gh  = (float*)(ws + 266240);        // 16 MB [4][256][4096]
  __bf16* xb  = (__bf16*)(ws + 17043456);     // 768 KB [256][1536]
  __bf16* hb  = (__bf16*)(ws + 17829888);     // 2 MB [4][256][1024]

  hipMemsetAsync(bar, 0, 4096, stream);
  k_scores<<<4096, 256, 0, stream>>>(AO, Wattn, sc);
  k_mid<<<1280, 512, 0, stream>>>(sc, AO, inp, Wemb, bemb, h0, Whh0, Whh_r,
                                  bih0, bhh0, bih_r, bhh_r, Gh,
                                  out + O_NORM, xb);
  k_tail<<<256, 512, 0, stream>>>(sc, AO, inp, Wemb, bemb, Wih0, Wih_r,
                                  Gh, c0, Wout, bout, out, bar, xb, hb);
}

// Round 17
// 152.093 us; speedup vs baseline: 1.6785x; 1.6785x over previous
//
#include <hip/hip_runtime.h>
#include <hip/hip_bf16.h>

typedef __bf16 bf16x8 __attribute__((ext_vector_type(8)));
typedef float  f32x4  __attribute__((ext_vector_type(4)));

// d_out offsets (floats)
#define O_FINAL 0
#define O_H     512
#define O_C     1049088      // 512 + 4*256*1024
#define O_NORM  2097664      // O_C + 4*256*1024

__device__ __forceinline__ bf16x8 cvt8(float4 a, float4 b) {
  bf16x8 r;
  r[0] = (__bf16)a.x; r[1] = (__bf16)a.y; r[2] = (__bf16)a.z; r[3] = (__bf16)a.w;
  r[4] = (__bf16)b.x; r[5] = (__bf16)b.y; r[6] = (__bf16)b.z; r[7] = (__bf16)b.w;
  return r;
}

// ============ ff staged core (R9-proven): 64 A-rows x [16c x 4g], 8 waves ============
template<int K>
__device__ __forceinline__ void tile_gemm_ff(const float* __restrict__ A,
                                             const float* __restrict__ W,
                                             int r0, int j0, char* lds,
                                             f32x4 acc[2]) {
  constexpr int NK = K / 64;
  constexpr int D = 4;
  const int t = threadIdx.x, lane = t & 63, wave = t >> 6;
  const int rf = wave & 3, gg = wave >> 2;
  const int tr = t >> 3, chunk = t & 7;
  const float* wsrc = W + (size_t)((tr >> 4) * 1024 + j0 + (tr & 15)) * K + chunk * 8;
  const float* asrc = A + (size_t)(r0 + tr) * K + chunk * 8;
  const int sw_off = (chunk ^ (tr & 7)) << 4;
  const int woff = 8192 + tr * 128 + sw_off;
  const int aoff = tr * 128 + sw_off;
  const int a_tr  = rf * 16 + (lane & 15);
  const int w_tr0 = gg * 32 + (lane & 15);
  const int w_tr1 = w_tr0 + 16;
  const int ksel  = lane >> 4;

  float4 wp[D][2], ap[D][2];
#pragma unroll
  for (int d = 0; d < D; ++d) {
    wp[d][0] = *(const float4*)(wsrc + d * 64);
    wp[d][1] = *(const float4*)(wsrc + d * 64 + 4);
    ap[d][0] = *(const float4*)(asrc + d * 64);
    ap[d][1] = *(const float4*)(asrc + d * 64 + 4);
  }
#pragma unroll
  for (int s = 0; s < NK; ++s) {
    const int sl = s % D;
    char* buf = lds + (s & 1) * 16384;
    *(bf16x8*)(buf + aoff) = cvt8(ap[sl][0], ap[sl][1]);
    *(bf16x8*)(buf + woff) = cvt8(wp[sl][0], wp[sl][1]);
    if (s + D < NK) {
      wp[sl][0] = *(const float4*)(wsrc + (s + D) * 64);
      wp[sl][1] = *(const float4*)(wsrc + (s + D) * 64 + 4);
      ap[sl][0] = *(const float4*)(asrc + (s + D) * 64);
      ap[sl][1] = *(const float4*)(asrc + (s + D) * 64 + 4);
    }
    __syncthreads();
#pragma unroll
    for (int s2 = 0; s2 < 2; ++s2) {
      const int chk = s2 * 4 + ksel;
      bf16x8 af  = *(const bf16x8*)(buf + a_tr * 128 + ((chk ^ (a_tr & 7)) << 4));
      bf16x8 wf0 = *(const bf16x8*)(buf + 8192 + w_tr0 * 128 + ((chk ^ (w_tr0 & 7)) << 4));
      bf16x8 wf1 = *(const bf16x8*)(buf + 8192 + w_tr1 * 128 + ((chk ^ (w_tr1 & 7)) << 4));
      acc[0] = __builtin_amdgcn_mfma_f32_16x16x32_bf16(af, wf0, acc[0], 0, 0, 0);
      acc[1] = __builtin_amdgcn_mfma_f32_16x16x32_bf16(af, wf1, acc[1], 0, 0, 0);
    }
  }
}

// ============ k_scores: pure scores, 4096 blocks x 256 thr (R3-proven) ============
__global__ __launch_bounds__(256) void k_scores(const float* __restrict__ AO,
                                                const float* __restrict__ Wattn,
                                                float* __restrict__ sc) {
  const int lane = threadIdx.x & 63, wave = threadIdx.x >> 6;
  const float* wy = Wattn + 1024;
  float4 wv[4];
#pragma unroll
  for (int q = 0; q < 4; ++q) wv[q] = *(const float4*)(wy + lane * 4 + 256 * q);
  const int row0 = (blockIdx.x * 4 + wave) * 4;
  float a4[4];
#pragma unroll
  for (int rr = 0; rr < 4; ++rr) {
    const float4* rp = (const float4*)(AO + (size_t)(row0 + rr) * 1024);
    float a = 0.f;
#pragma unroll
    for (int q = 0; q < 4; ++q) {
      float4 v = rp[lane + 64 * q];
      a += v.x * wv[q].x + v.y * wv[q].y + v.z * wv[q].z + v.w * wv[q].w;
    }
    a4[rr] = a;
  }
#pragma unroll
  for (int rr = 0; rr < 4; ++rr) {
    float a = a4[rr];
#pragma unroll
    for (int off = 32; off; off >>= 1) a += __shfl_xor(a, off, 64);
    if (lane == 0) {
      int row = row0 + rr;                      // row = pos*256 + b
      sc[(row & 255) * 256 + (row >> 8)] = a;   // [b][pos]
    }
  }
}

// ============ k_mid: Gh (blocks 0..1023) | smx-512 (1024..1279) ============
__global__ __launch_bounds__(512) void k_mid(
    const float* __restrict__ sc,   const float* __restrict__ AO,
    const float* __restrict__ inp,  const float* __restrict__ Wemb,
    const float* __restrict__ bemb,
    const float* __restrict__ h0,
    const float* __restrict__ Whh0, const float* __restrict__ Whh_r,
    const float* __restrict__ bih0, const float* __restrict__ bhh0,
    const float* __restrict__ bih_r, const float* __restrict__ bhh_r,
    float* __restrict__ Gh,
    float* __restrict__ norm_out,   __bf16* __restrict__ xb) {
  __shared__ char smem[32768];
  const int t = threadIdx.x, lane = t & 63, wave = t >> 6;
  if (blockIdx.x < 1024) {
    const int j = blockIdx.x;
    const int l = j >> 8, inner = j & 255;
    const int cb = inner & 63, rb = inner >> 6;
    const int j0 = cb * 16, r0 = rb * 64;
    const float* A  = h0 + (size_t)l * 262144;
    const float* W  = (l == 0) ? Whh0 : (Whh_r + (size_t)(l - 1) * 4194304);
    const float* bi = (l == 0) ? bih0 : (bih_r + (size_t)(l - 1) * 4096);
    const float* bh = (l == 0) ? bhh0 : (bhh_r + (size_t)(l - 1) * 4096);
    f32x4 acc[2] = {};
    tile_gemm_ff<1024>(A, W, r0, j0, smem, acc);
    float* Go = Gh + (size_t)l * 1048576;
    const int rf = wave & 3, gg = wave >> 2;
    const int col = j0 + (lane & 15);
    const int rbase = r0 + rf * 16 + ((lane >> 4) << 2);
#pragma unroll
    for (int gi = 0; gi < 2; ++gi) {
      const int cg = (gg * 2 + gi) * 1024 + col;
#pragma unroll
      for (int q = 0; q < 4; ++q)
        Go[(size_t)(rbase + q) * 4096 + cg] = acc[gi][q] + bi[cg] + bh[cg];
    }
    return;
  }
  // smx at 512 thr
  float* red  = (float*)smem;
  float* nv_l = (float*)(smem + 64);
  const int b = blockIdx.x - 1024;
  float s = (t < 256) ? sc[b * 256 + t] : -3.4e38f;
  float m = s;
#pragma unroll
  for (int off = 32; off; off >>= 1) m = fmaxf(m, __shfl_xor(m, off, 64));
  if (lane == 0) red[wave] = m;
  __syncthreads();
  m = red[0];
#pragma unroll
  for (int w2 = 1; w2 < 8; ++w2) m = fmaxf(m, red[w2]);
  float e = (t < 256) ? __expf(s - m) : 0.f;
  float sum = e;
#pragma unroll
  for (int off = 32; off; off >>= 1) sum += __shfl_xor(sum, off, 64);
  __syncthreads();
  if (lane == 0) red[wave] = sum;
  __syncthreads();
  sum = red[0];
#pragma unroll
  for (int w2 = 1; w2 < 8; ++w2) sum += red[w2];
  float nv = e / sum;
  if (t < 256) {
    norm_out[b * 256 + t] = nv;
    if (t >= 224) nv_l[t - 224] = nv;
  }
  __syncthreads();
  float a0 = 0.f, a1 = 0.f;
  const float* base = AO + ((size_t)224 * 256 + b) * 1024;
#pragma unroll 4
  for (int i = 0; i < 32; ++i) {
    float w = nv_l[i];
    const float* rp = base + (size_t)i * 262144;
    a0 += w * rp[t];
    a1 += w * rp[t + 512];
  }
  xb[(size_t)b * 1536 + t]       = (__bf16)(8.0f * a0);
  xb[(size_t)b * 1536 + t + 512] = (__bf16)(8.0f * a1);
  float e2 = inp[b * 2] * Wemb[t * 2] + inp[b * 2 + 1] * Wemb[t * 2 + 1] + bemb[t];
  xb[(size_t)b * 1536 + 1024 + t] = (__bf16)fmaxf(e2, 0.f);
}

// ============ k_layer: 256 blocks x 512 thr, 64-row x [16c x 4g] tiles ============
template<int KA>
__global__ __launch_bounds__(512) void k_layer(const __bf16* __restrict__ A,
                                               const float* __restrict__ Wih,
                                               const float* __restrict__ Gh,
                                               const float* __restrict__ c0l,
                                               float* __restrict__ h_out,
                                               float* __restrict__ c_out,
                                               __bf16* __restrict__ hb) {
  __shared__ char smem[40960];
  float* exch = (float*)(smem + 32768);     // [4*2][256] floats = 8 KB
  const int t = threadIdx.x, lane = t & 63, wave = t >> 6;
  const int rf = wave & 3, gg = wave >> 2;
  const int cb = blockIdx.x & 63, rb = blockIdx.x >> 6;
  const int j0 = cb * 16, r0 = rb * 64;
  // inline bf-gemm: A bf16, W fp32 (cvt in staging), D=4, dbuf, 1 sync/step
  {
    constexpr int NK = KA / 64;
    constexpr int D = 4;
    const int tr = t >> 3, chunk = t & 7;
    const float*  wsrc = Wih + (size_t)((tr >> 4) * 1024 + j0 + (tr & 15)) * KA + chunk * 8;
    const __bf16* asrc = A + (size_t)(r0 + tr) * KA + chunk * 8;
    const int sw_off = (chunk ^ (tr & 7)) << 4;
    const int woff = 8192 + tr * 128 + sw_off;
    const int aoff = tr * 128 + sw_off;
    const int a_tr  = rf * 16 + (lane & 15);
    const int w_tr0 = gg * 32 + (lane & 15);
    const int w_tr1 = w_tr0 + 16;
    const int ksel  = lane >> 4;
    f32x4 acc[2] = {};
    float4 wp[D][2]; bf16x8 ap[D];
#pragma unroll
    for (int d = 0; d < D; ++d) {
      wp[d][0] = *(const float4*)(wsrc + d * 64);
      wp[d][1] = *(const float4*)(wsrc + d * 64 + 4);
      ap[d]    = *(const bf16x8*)(asrc + d * 64);
    }
#pragma unroll
    for (int s = 0; s < NK; ++s) {
      const int sl = s % D;
      char* buf = smem + (s & 1) * 16384;
      *(bf16x8*)(buf + aoff) = ap[sl];
      *(bf16x8*)(buf + woff) = cvt8(wp[sl][0], wp[sl][1]);
      if (s + D < NK) {
        wp[sl][0] = *(const float4*)(wsrc + (s + D) * 64);
        wp[sl][1] = *(const float4*)(wsrc + (s + D) * 64 + 4);
        ap[sl]    = *(const bf16x8*)(asrc + (s + D) * 64);
      }
      __syncthreads();
#pragma unroll
      for (int s2 = 0; s2 < 2; ++s2) {
        const int chk = s2 * 4 + ksel;
        bf16x8 af  = *(const bf16x8*)(buf + a_tr * 128 + ((chk ^ (a_tr & 7)) << 4));
        bf16x8 wf0 = *(const bf16x8*)(buf + 8192 + w_tr0 * 128 + ((chk ^ (w_tr0 & 7)) << 4));
        bf16x8 wf1 = *(const bf16x8*)(buf + 8192 + w_tr1 * 128 + ((chk ^ (w_tr1 & 7)) << 4));
        acc[0] = __builtin_amdgcn_mfma_f32_16x16x32_bf16(af, wf0, acc[0], 0, 0, 0);
        acc[1] = __builtin_amdgcn_mfma_f32_16x16x32_bf16(af, wf1, acc[1], 0, 0, 0);
      }
    }
    // epilogue
    const int col = j0 + (lane & 15);
    const int rbase = r0 + rf * 16 + ((lane >> 4) << 2);
    const int eidx = ((lane >> 4) << 2) * 16 + (lane & 15);
#pragma unroll
    for (int gi = 0; gi < 2; ++gi) {
      const float* gp = Gh + (size_t)rbase * 4096 + (gg * 2 + gi) * 1024 + col;
#pragma unroll
      for (int q = 0; q < 4; ++q) acc[gi][q] += gp[(size_t)q * 4096];
    }
    __syncthreads();
    if (gg == 1) {
#pragma unroll
      for (int gi = 0; gi < 2; ++gi)
#pragma unroll
        for (int q = 0; q < 4; ++q)
          exch[(rf * 2 + gi) * 256 + eidx + q * 16] = acc[gi][q];
    }
    __syncthreads();
    if (gg == 0) {
#pragma unroll
      for (int q = 0; q < 4; ++q) {
        const int row = rbase + q;
        float gv = exch[(rf * 2 + 0) * 256 + eidx + q * 16];
        float ov = exch[(rf * 2 + 1) * 256 + eidx + q * 16];
        float si = 1.f / (1.f + __expf(-acc[0][q]));
        float sf = 1.f / (1.f + __expf(-acc[1][q]));
        float so = 1.f / (1.f + __expf(-ov));
        float c2 = sf * c0l[(size_t)row * 1024 + col] + si * tanhf(gv);
        float h2 = so * tanhf(c2);
        h_out[(size_t)row * 1024 + col] = h2;
        c_out[(size_t)row * 1024 + col] = c2;
        hb[(size_t)row * 1024 + col] = (__bf16)h2;
      }
    }
  }
}

// ============ k_final ============
__global__ __launch_bounds__(256) void k_final(const float* __restrict__ h3,
                                               const float* __restrict__ Wout,
                                               const float* __restrict__ bout,
                                               float* __restrict__ out) {
  const int lane = threadIdx.x & 63, wave = threadIdx.x >> 6;
  const int b = blockIdx.x * 4 + wave;
  const float4* hp = (const float4*)(h3 + (size_t)b * 1024);
  const float4* w0 = (const float4*)Wout;
  const float4* w1 = (const float4*)(Wout + 1024);
  float a0 = 0.f, a1 = 0.f;
#pragma unroll
  for (int q = 0; q < 4; ++q) {
    float4 hv = hp[lane + 64 * q];
    float4 v0 = w0[lane + 64 * q];
    float4 v1 = w1[lane + 64 * q];
    a0 += hv.x * v0.x + hv.y * v0.y + hv.z * v0.z + hv.w * v0.w;
    a1 += hv.x * v1.x + hv.y * v1.y + hv.z * v1.z + hv.w * v1.w;
  }
#pragma unroll
  for (int off = 32; off; off >>= 1) {
    a0 += __shfl_xor(a0, off, 64);
    a1 += __shfl_xor(a1, off, 64);
  }
  if (lane == 0) {
    out[b * 2]     = a0 + bout[0];
    out[b * 2 + 1] = a1 + bout[1];
  }
}

extern "C" void kernel_launch(void* const* d_in, const int* in_sizes, int n_in,
                              void* d_out, int out_size, void* d_ws, size_t ws_size,
                              hipStream_t stream) {
  const float* inp    = (const float*)d_in[0];
  const float* h0     = (const float*)d_in[1];
  const float* c0     = (const float*)d_in[2];
  const float* AO     = (const float*)d_in[3];
  const float* Wemb   = (const float*)d_in[4];
  const float* bemb   = (const float*)d_in[5];
  const float* Wattn  = (const float*)d_in[6];
  // d_in[7] = b_attn (cancels in softmax)
  const float* Wih0   = (const float*)d_in[8];
  const float* Whh0   = (const float*)d_in[9];
  const float* bih0   = (const float*)d_in[10];
  const float* bhh0   = (const float*)d_in[11];
  const float* Wih_r  = (const float*)d_in[12];
  const float* Whh_r  = (const float*)d_in[13];
  const float* bih_r  = (const float*)d_in[14];
  const float* bhh_r  = (const float*)d_in[15];
  const float* Wout   = (const float*)d_in[16];
  const float* bout   = (const float*)d_in[17];

  float* out = (float*)d_out;
  char* ws = (char*)d_ws;

  float*  sc = (float*)ws;                    // 256 KB [256][256]
  float*  Gh = (float*)(ws + 262144);         // 16 MB [4][256][4096]
  __bf16* xb = (__bf16*)(ws + 17039360);      // 768 KB [256][1536]
  __bf16* hb = (__bf16*)(ws + 17825792);      // 2 MB [4][256][1024]

  k_scores<<<4096, 256, 0, stream>>>(AO, Wattn, sc);
  k_mid<<<1280, 512, 0, stream>>>(sc, AO, inp, Wemb, bemb, h0, Whh0, Whh_r,
                                  bih0, bhh0, bih_r, bhh_r, Gh,
                                  out + O_NORM, xb);

  k_layer<1536><<<256, 512, 0, stream>>>(xb, Wih0, Gh, c0,
                                         out + O_H, out + O_C, hb);
  for (int l = 1; l < 4; ++l)
    k_layer<1024><<<256, 512, 0, stream>>>(hb + (size_t)(l - 1) * 262144,
                                           Wih_r + (size_t)(l - 1) * 4194304,
                                           Gh + (size_t)l * 1048576,
                                           c0 + (size_t)l * 262144,
                                           out + O_H + (size_t)l * 262144,
                                           out + O_C + (size_t)l * 262144,
                                           hb + (size_t)l * 262144);

  k_final<<<64, 256, 0, stream>>>(out + O_H + 3 * 262144, Wout, bout, out + O_FINAL);
}